// Round 6
// baseline (342.227 us; speedup 1.0000x reference)
//
#include <hip/hip_runtime.h>
#include <float.h>
#include <math.h>

#define B_  8
#define H_  8
#define L_  2048
#define D_  64
#define NS  40          // num selected = min(5*ceil(ln(2048)), 2048) = 40
#define BH  (B_*H_)
#define SCALE 0.125f    // d^-0.5

// XCD swizzle: block b -> XCD (b%8); we arrange bh%8 == b%8 so each bh's
// k/v/measure/attn slices stay resident in one XCD's 4MB L2 (validated R5:
// FETCH 147->34 MB on measure).

// DPP lane-move (VALU-rate, no LDS): 0xB1=xor1, 0x4E=xor2, 0x124=row_ror:4,
// 0x128=row_ror:8, 0x142=row_bcast15, 0x143=row_bcast31.
template<int CTRL>
__device__ __forceinline__ float dpp_mov(float x) {
    return __int_as_float(__builtin_amdgcn_update_dpp(
        0, __float_as_int(x), CTRL, 0xf, 0xf, true));
}

// ---------------------------------------------------------------------------
// Kernel A: measure (blocks 0..32767)  U  cumsum_p1 (blocks 32768..33791).
// measure: one wave/query, quarter-wave row gather, all-DPP reduction
// (zero DS ops/wave; R5 showed ~54 shuffles/wave were the bottleneck).
// ---------------------------------------------------------------------------
__global__ __launch_bounds__(256) void kernelA(
    const float* __restrict__ q, const float* __restrict__ k,
    const int* __restrict__ ridx, const float* __restrict__ v,
    float* __restrict__ measure, float4* __restrict__ vpart)
{
    if (blockIdx.x < 32768) {
        // ---- measure ----
        int wave = threadIdx.x >> 6, lane = threadIdx.x & 63;
        int b = blockIdx.x;
        int xcd = b & 7, s = b >> 3;          // s in 0..4095
        int bh  = xcd + ((s >> 9) << 3);      // 8 bh per XCD, sequential
        int i   = (s & 511) * 4 + wave;
        int qj  = lane >> 4;                  // quarter 0..3
        int d4  = lane & 15;

        const float4* kb = (const float4*)(k + (size_t)bh * L_ * D_);
        float4 qq = ((const float4*)(q + ((size_t)bh * L_ + i) * D_))[d4];
        const int* rip = ridx + i * NS + qj;  // quarter-uniform loads

        float mx = -FLT_MAX, sm = 0.f;
        #pragma unroll
        for (int p = 0; p < 10; ++p) {
            int r = rip[p * 4];                      // 1 line/wave, no shuffle
            float4 kk = kb[(size_t)r * 16 + d4];     // 16 lanes cover the row
            float pp = qq.x*kk.x + qq.y*kk.y + qq.z*kk.z + qq.w*kk.w;
            pp += dpp_mov<0xB1>(pp);                 // xor1 (quad_perm)
            pp += dpp_mov<0x4E>(pp);                 // xor2 (quad_perm)
            pp += dpp_mov<0x124>(pp);                // row_ror:4
            pp += dpp_mov<0x128>(pp);                // row_ror:8 -> 16-lane dot
            mx = fmaxf(mx, pp);
            sm += pp;
        }
        // cross-quarter combine; valid result lands in lane 63
        mx = fmaxf(mx, dpp_mov<0x142>(mx));  sm += dpp_mov<0x142>(sm);
        mx = fmaxf(mx, dpp_mov<0x143>(mx));  sm += dpp_mov<0x143>(sm);
        if (lane == 63)
            measure[(size_t)bh * L_ + i] = mx - sm * (1.0f / (float)L_);
    } else {
        // ---- cumsum_p1 ----
        __shared__ float4 part[16][16];
        int b = blockIdx.x - 32768;
        int xcd = b & 7, s = b >> 3;
        int bh = xcd + ((s >> 4) << 3);
        int c  = s & 15;
        int d4 = threadIdx.x & 15, sub = threadIdx.x >> 4;
        const float4* vb = (const float4*)(v + (size_t)bh * L_ * D_);
        int r0 = c*128 + sub*8;
        float4 acc = make_float4(0,0,0,0);
        #pragma unroll
        for (int r = 0; r < 8; ++r) {
            float4 x = vb[(r0 + r)*16 + d4];
            acc.x += x.x; acc.y += x.y; acc.z += x.z; acc.w += x.w;
        }
        part[sub][d4] = acc;
        __syncthreads();
        if (sub == 0) {
            float4 tot = part[0][d4];
            #pragma unroll
            for (int ss = 1; ss < 16; ++ss) {
                float4 x = part[ss][d4];
                tot.x += x.x; tot.y += x.y; tot.z += x.z; tot.w += x.w;
            }
            vpart[(bh*16 + c)*16 + d4] = tot;
        }
    }
}

// ---------------------------------------------------------------------------
// Kernel B: topk (blocks 0..63)  U  cumsum_p2 (blocks 64..1087).
// ---------------------------------------------------------------------------
__global__ __launch_bounds__(256) void kernelB(
    const float* __restrict__ measure, const float* __restrict__ v,
    const float4* __restrict__ vpart, int* __restrict__ idxOut,
    float* __restrict__ out)
{
    if (blockIdx.x < 64) {
        // ---- topk ----
        __shared__ float wv[4]; __shared__ int wi[4];
        __shared__ int biS;
        int bh = blockIdx.x, t = threadIdx.x;
        const float4* m4 = (const float4*)(measure + (size_t)bh * L_);
        float vals[8];
        float4 a = m4[t*2], bb = m4[t*2 + 1];
        vals[0]=a.x; vals[1]=a.y; vals[2]=a.z; vals[3]=a.w;
        vals[4]=bb.x; vals[5]=bb.y; vals[6]=bb.z; vals[7]=bb.w;

        float lv = -FLT_MAX; int li = t*8;
        #pragma unroll
        for (int e = 0; e < 8; ++e) if (vals[e] > lv) { lv = vals[e]; li = t*8 + e; }

        int lane = t & 63, w = t >> 6;
        for (int r = 0; r < NS; ++r) {
            float vv = lv; int idx = li;
            #pragma unroll
            for (int off = 32; off; off >>= 1) {
                float ov = __shfl_xor(vv, off, 64);
                int   oi = __shfl_xor(idx, off, 64);
                if (ov > vv || (ov == vv && oi < idx)) { vv = ov; idx = oi; }
            }
            if (lane == 0) { wv[w] = vv; wi[w] = idx; }
            __syncthreads();
            if (t == 0) {
                float bv = wv[0]; int bi = wi[0];
                #pragma unroll
                for (int ww = 1; ww < 4; ++ww)
                    if (wv[ww] > bv || (wv[ww] == bv && wi[ww] < bi)) { bv = wv[ww]; bi = wi[ww]; }
                biS = bi;
                idxOut[bh * NS + r] = bi;
            }
            __syncthreads();
            int bi = biS;
            if ((bi >> 3) == t) {
                #pragma unroll
                for (int e = 0; e < 8; ++e) if ((bi & 7) == e) vals[e] = -FLT_MAX;
                lv = -FLT_MAX; li = t*8;
                #pragma unroll
                for (int e = 0; e < 8; ++e) if (vals[e] > lv) { lv = vals[e]; li = t*8 + e; }
            }
            __syncthreads();
        }
    } else {
        // ---- cumsum_p2 ----
        __shared__ float4 part[16][16];
        int b = blockIdx.x - 64;
        int xcd = b & 7, s = b >> 3;
        int bh = xcd + ((s >> 4) << 3);
        int c  = s & 15;
        int d4 = threadIdx.x & 15, sub = threadIdx.x >> 4;
        const float4* vb = (const float4*)(v + (size_t)bh * L_ * D_);
        float4*       ob = (float4*)(out + (size_t)bh * L_ * D_);
        int r0 = c*128 + sub*8;
        float4 acc = make_float4(0,0,0,0);
        #pragma unroll
        for (int r = 0; r < 8; ++r) {
            float4 x = vb[(r0 + r)*16 + d4];
            acc.x += x.x; acc.y += x.y; acc.z += x.z; acc.w += x.w;
        }
        part[sub][d4] = acc;
        float4 run = make_float4(0,0,0,0);
        for (int cc = 0; cc < c; ++cc) {
            float4 x = vpart[(bh*16 + cc)*16 + d4];
            run.x += x.x; run.y += x.y; run.z += x.z; run.w += x.w;
        }
        __syncthreads();
        #pragma unroll
        for (int ss = 0; ss < 16; ++ss) {
            if (ss < sub) {
                float4 x = part[ss][d4];
                run.x += x.x; run.y += x.y; run.z += x.z; run.w += x.w;
            }
        }
        #pragma unroll
        for (int r = 0; r < 8; ++r) {
            float4 x = vb[(r0 + r)*16 + d4];
            run.x += x.x; run.y += x.y; run.z += x.z; run.w += x.w;
            ob[(r0 + r)*16 + d4] = run;
        }
    }
}

// ---------------------------------------------------------------------------
// Kernel C: scores + softmax + PV fused.  Block = (bh, group of 4 ranks),
// one wave per rank.  Scores via LDS-staged k chunks; masked softmax
// wave-local; normalized weights -> global attn output AND block LDS; then
// the same block does PV for its 4 ranks (v f4 read once per 4 ranks) and
// overwrites out[bh, qrow, :].
// ---------------------------------------------------------------------------
__global__ __launch_bounds__(256) void kernelC(
    const float* __restrict__ q, const float* __restrict__ k,
    const float* __restrict__ v, const int* __restrict__ idxSel,
    float* __restrict__ out, float* __restrict__ attn)
{
    __shared__ float4 kbuf[16 * 129];   // [g][j], stride 129 f4 (33 KB)
    __shared__ float wl[4][L_ + 64];    // per-rank weights, pad j+4*(j>>7) (34 KB)
    __shared__ float4 part[16][16];
    __shared__ int qr4[4];
    int b = blockIdx.x;
    int xcd = b & 7, s = b >> 3;          // s in 0..79
    int bh  = xcd + ((s / 10) << 3);
    int grp = s % 10;
    int qi = threadIdx.x >> 6, sub = threadIdx.x & 63;
    int rank = grp*4 + qi;
    int qrow = idxSel[bh*NS + rank];
    if (sub == 0) qr4[qi] = qrow;

    const float4* qrp = (const float4*)(q + ((size_t)bh * L_ + qrow) * D_);
    float4 qreg[16];
    #pragma unroll
    for (int g = 0; g < 16; ++g) qreg[g] = qrp[g];    // wave-uniform

    const float4* kb = (const float4*)(k + (size_t)bh * L_ * D_);
    float sc0[16], sc1[16];

    #pragma unroll
    for (int c = 0; c < 16; ++c) {
        __syncthreads();                               // kbuf reuse guard
        int j0 = c * 128;
        #pragma unroll
        for (int it = 0; it < 8; ++it) {               // coalesced stage
            int fi = threadIdx.x + 256*it;
            int g = fi & 15, j = fi >> 4;
            kbuf[g*129 + j] = kb[(size_t)(j0 + j)*16 + g];
        }
        __syncthreads();
        float acc0 = 0.f, acc1 = 0.f;
        #pragma unroll
        for (int g = 0; g < 16; ++g) {
            float4 k0 = kbuf[g*129 + sub];             // dense b128
            float4 k1 = kbuf[g*129 + sub + 64];
            float4 qq = qreg[g];
            acc0 += qq.x*k0.x + qq.y*k0.y + qq.z*k0.z + qq.w*k0.w;
            acc1 += qq.x*k1.x + qq.y*k1.y + qq.z*k1.z + qq.w*k1.w;
        }
        sc0[c] = acc0 * SCALE;
        sc1[c] = acc1 * SCALE;
    }

    // masked softmax, wave-local
    float mx = -FLT_MAX;
    #pragma unroll
    for (int c = 0; c < 16; ++c) {
        if (c*128 + sub      <= qrow) mx = fmaxf(mx, sc0[c]);
        if (c*128 + sub + 64 <= qrow) mx = fmaxf(mx, sc1[c]);
    }
    #pragma unroll
    for (int off = 32; off; off >>= 1) mx = fmaxf(mx, __shfl_xor(mx, off, 64));

    float sum = 0.f;
    #pragma unroll
    for (int c = 0; c < 16; ++c) {
        sc0[c] = (c*128 + sub      <= qrow) ? __expf(sc0[c] - mx) : 0.f;
        sc1[c] = (c*128 + sub + 64 <= qrow) ? __expf(sc1[c] - mx) : 0.f;
        sum += sc0[c] + sc1[c];
    }
    #pragma unroll
    for (int off = 32; off; off >>= 1) sum += __shfl_xor(sum, off, 64);
    float inv = 1.f / sum;

    // write normalized weights: global attn output + block LDS for PV
    float* arow = attn + (size_t)(bh*NS + rank) * L_;
    #pragma unroll
    for (int c = 0; c < 16; ++c) {
        float w0 = sc0[c] * inv, w1 = sc1[c] * inv;
        int j0 = c*128 + sub, j1 = c*128 + sub + 64;
        arow[j0] = w0;                                 // coalesced
        arow[j1] = w1;
        wl[qi][j0 + 4*(j0 >> 7)] = w0;
        wl[qi][j1 + 4*(j1 >> 7)] = w1;
    }
    __syncthreads();

    // ---- PV: out[bh, qrow_r, :] = wl[r] @ v, v f4 read once per 4 ranks ----
    int t = threadIdx.x;
    int maxq = max(max(qr4[0], qr4[1]), max(qr4[2], qr4[3]));
    int d4 = t & 15, seg = t >> 4;
    const float4* vb = (const float4*)(v + (size_t)bh * L_ * D_);
    float4 acc[4];
    #pragma unroll
    for (int rr = 0; rr < 4; ++rr) acc[rr] = make_float4(0,0,0,0);

    int jlo = seg*128, jhi = min(jlo + 127, maxq);
    for (int j = jlo; j <= jhi; ++j) {
        float4 x = vb[(size_t)j*16 + d4];
        int jp = j + 4*(j >> 7);
        #pragma unroll
        for (int rr = 0; rr < 4; ++rr) {
            float wgt = wl[rr][jp];                    // 2-way conflict (free)
            acc[rr].x += wgt*x.x; acc[rr].y += wgt*x.y;
            acc[rr].z += wgt*x.z; acc[rr].w += wgt*x.w;
        }
    }

    #pragma unroll
    for (int rr = 0; rr < 4; ++rr) {
        part[seg][d4] = acc[rr];
        __syncthreads();
        float4 a = acc[rr];
        for (int s2 = 8; s2; s2 >>= 1) {
            if (seg < s2) {
                float4 o = part[seg + s2][d4];
                a.x += o.x; a.y += o.y; a.z += o.z; a.w += o.w;
                part[seg][d4] = a;
            }
            __syncthreads();
        }
        if (seg == 0) {
            float4* orow = (float4*)(out + ((size_t)bh * L_ + qr4[rr]) * D_);
            orow[d4] = a;
        }
        __syncthreads();
    }
}

// ---------------------------------------------------------------------------
extern "C" void kernel_launch(void* const* d_in, const int* in_sizes, int n_in,
                              void* d_out, int out_size, void* d_ws, size_t ws_size,
                              hipStream_t stream) {
    const float* q    = (const float*)d_in[0];
    const float* k    = (const float*)d_in[1];
    const float* v    = (const float*)d_in[2];
    const int*   ridx = (const int*)d_in[3];

    float* out     = (float*)d_out;                    // (B,H,L,D)
    float* attnOut = out + (size_t)BH * L_ * D_;       // (B,H,NS,L)

    // non-aliasing workspace layout (p1 runs concurrently with measure now)
    float*  measure = (float*)d_ws;                                  // 512 KB
    float4* vpart   = (float4*)((char*)d_ws + 524288);               // 256 KB
    int*    idxSel  = (int*)((char*)d_ws + 524288 + 262144);         //  10 KB

    kernelA<<<32768 + 1024, 256, 0, stream>>>(q, k, ridx, v, measure, vpart);
    kernelB<<<64 + 1024,    256, 0, stream>>>(measure, v, vpart, idxSel, out);
    kernelC<<<BH * 10,      256, 0, stream>>>(q, k, v, idxSel, out, attnOut);
}